// Round 1
// baseline (710.521 us; speedup 1.0000x reference)
//
#include <hip/hip_runtime.h>

#define B_ROWS   131072
#define MTILE    32
#define KCHUNKS  17        // 544 / 32
// ws layout: [0, 512KB) mask u32; [512KB, +557056) W1t fp16 [512][544]
#define W1T_OFF  ((size_t)B_ROWS * 4)

typedef _Float16 f16x8 __attribute__((ext_vector_type(8)));
typedef float    f32x4 __attribute__((ext_vector_type(4)));

__device__ inline unsigned short f2h(float f) {
  _Float16 h = (_Float16)f;
  return __builtin_bit_cast(unsigned short, h);
}
__device__ inline float selu_f(float x) {
  const float lam = 1.0507009873554805f, alp = 1.6732632423543772f;
  return x > 0.f ? lam * x : lam * alp * (__expf(x) - 1.f);
}
__device__ inline void gld16(const void* g, void* l) {
  __builtin_amdgcn_global_load_lds(
      (const __attribute__((address_space(1))) unsigned int*)g,
      (__attribute__((address_space(3))) unsigned int*)l, 16, 0, 0);
}

__global__ void scatter_mask(const int* __restrict__ coords,
                             unsigned int* __restrict__ mask) {
  int i = blockIdx.x * 256 + threadIdx.x;
  mask[coords[i]] = 1u;
}

// W1 fp32 [526][512] -> W1t fp16 [n=512][k=544], K-permuted:
//   k<512: feature weights (orig row k+14); 512<=k<526: jnt rows (orig row k-512); else 0
__global__ void build_w1t(const float* __restrict__ W1,
                          unsigned short* __restrict__ W1t) {
  int n = blockIdx.x;      // 0..511
  int k = threadIdx.x;     // 0..543
  float v = 0.f;
  if (k < 512)       v = W1[(size_t)(k + 14) * 512 + n];
  else if (k < 526)  v = W1[(size_t)(k - 512) * 512 + n];
  W1t[(size_t)n * 544 + k] = f2h(v);
}

struct __align__(16) SMem {
  // union region: K-loop At[32][40] (2560B) + Bt[512][32] (32768B) = 35328B
  //               epilogue x2[32][520] fp16 = 33280B
  char buf[35328];
  float mean1[MTILE], rstd1[MTILE], maskf[MTILE];
  float rsum[MTILE], rsq[MTILE], mean2[MTILE], rstd2[MTILE];
};

__global__ __launch_bounds__(256) void actor_main(
    const float* __restrict__ feat, const unsigned int* __restrict__ mask,
    const float* __restrict__ jp, const float* __restrict__ jg,
    const float* __restrict__ ln1g, const float* __restrict__ ln1b,
    const unsigned short* __restrict__ W1t, const float* __restrict__ b1,
    const float* __restrict__ ln2g, const float* __restrict__ ln2b,
    const float* __restrict__ W2, const float* __restrict__ b2,
    float* __restrict__ out) {
  __shared__ SMem sm;
  unsigned short* At = (unsigned short*)sm.buf;            // [32][40] fp16, padded
  unsigned short* Bt = (unsigned short*)(sm.buf + 2560);   // [512][32] fp16, UNPADDED (global_load_lds)
  unsigned short* X2 = (unsigned short*)sm.buf;            // [32][520] fp16 (epilogue union)

  const int tid  = threadIdx.x;
  const int wave = tid >> 6;
  const int lane = tid & 63;
  const int m0   = blockIdx.x * MTILE;
  const int mrow = lane & 15;
  const int quad = lane >> 4;

  // ---------- phase 0: LN1 row stats (wave = 8 rows) ----------
  const float4* f4 = (const float4*)feat;
  for (int i = 0; i < 8; ++i) {
    int lr = wave * 8 + i;
    int row = m0 + lr;
    float4 a = f4[(size_t)row * 128 + lane * 2];
    float4 b = f4[(size_t)row * 128 + lane * 2 + 1];
    float s = a.x + a.y + a.z + a.w + b.x + b.y + b.z + b.w;
    float q = a.x * a.x + a.y * a.y + a.z * a.z + a.w * a.w +
              b.x * b.x + b.y * b.y + b.z * b.z + b.w * b.w;
#pragma unroll
    for (int d = 32; d > 0; d >>= 1) { s += __shfl_xor(s, d); q += __shfl_xor(q, d); }
    if (lane == 0) {
      float mk   = mask[row] ? 1.f : 0.f;  // masked-out row => y=0 => LN -> b -> selu(b)
      float mean = mk * s * (1.f / 512.f);
      float msq  = mk * q * (1.f / 512.f);
      sm.mean1[lr] = mean;
      sm.rstd1[lr] = rsqrtf(msq - mean * mean + 1e-5f);
      sm.maskf[lr] = mk;
    }
  }
  if (tid < MTILE) { sm.rsum[tid] = 0.f; sm.rsq[tid] = 0.f; }
  __syncthreads();

  // ---------- K loop: 17 chunks of BK=32 ----------
  f32x4 acc[2][8];
#pragma unroll
  for (int mi = 0; mi < 2; ++mi)
#pragma unroll
    for (int ni = 0; ni < 8; ++ni) acc[mi][ni] = (f32x4){0.f, 0.f, 0.f, 0.f};

  const int arow = tid >> 3;  // 0..31
  const int acg  = tid & 7;   // 0..7  (4 cols each)

  for (int c = 0; c < KCHUNKS; ++c) {
    if (c) __syncthreads();  // protect LDS rewrite vs prev chunk's frag reads

    // --- A tile: LN1+SELU fused (chunks 0..15 = features; 16 = jnt concat) ---
    float v0, v1, v2, v3;
    if (c < 16) {
      float4 f    = f4[(size_t)(m0 + arow) * 128 + c * 8 + acg];
      float mk    = sm.maskf[arow], mean = sm.mean1[arow], rstd = sm.rstd1[arow];
      float4 g    = ((const float4*)ln1g)[c * 8 + acg];
      float4 b    = ((const float4*)ln1b)[c * 8 + acg];
      v0 = selu_f((f.x * mk - mean) * rstd * g.x + b.x);
      v1 = selu_f((f.y * mk - mean) * rstd * g.y + b.y);
      v2 = selu_f((f.z * mk - mean) * rstd * g.z + b.z);
      v3 = selu_f((f.w * mk - mean) * rstd * g.w + b.w);
    } else {
      int row = m0 + arow;
      float t[4];
#pragma unroll
      for (int q2 = 0; q2 < 4; ++q2) {
        int kk = acg * 4 + q2;  // local col in [0,32) -> global K 512+kk
        float val = 0.f;
        if (kk < 7)       val = jp[(size_t)row * 7 + kk];
        else if (kk < 14) val = jg[(size_t)row * 7 + kk - 7];
        t[q2] = val;
      }
      v0 = t[0]; v1 = t[1]; v2 = t[2]; v3 = t[3];
    }
    {
      union { unsigned short us[4]; uint2 u; } pk;
      pk.us[0] = f2h(v0); pk.us[1] = f2h(v1); pk.us[2] = f2h(v2); pk.us[3] = f2h(v3);
      *(uint2*)&At[arow * 40 + acg * 4] = pk.u;
    }

    // --- B tile: W1t[:, c*32..+32) -> Bt[512][32] via global_load_lds width=16 ---
    {
      const char* wb = (const char*)W1t + (size_t)c * 64;
      char* lb = (char*)Bt + (size_t)(wave * 64) * 16;  // wave-uniform base
#pragma unroll
      for (int i = 0; i < 8; ++i) {
        int slot = i * 256 + tid;  // slot*16B == Bt byte offset == (slot>>2)*64 + (slot&3)*16
        gld16(wb + (size_t)(slot >> 2) * 1088 + (size_t)(slot & 3) * 16,
              lb + (size_t)i * 4096);
      }
    }
    __syncthreads();

    // --- fragments + MFMA (wave: rows 0..31 x cols wave*128..+128) ---
    f16x8 aF[2], bF[8];
#pragma unroll
    for (int mi = 0; mi < 2; ++mi)
      aF[mi] = *(const f16x8*)&At[(mi * 16 + mrow) * 40 + quad * 8];
#pragma unroll
    for (int ni = 0; ni < 8; ++ni)
      bF[ni] = *(const f16x8*)&Bt[(wave * 128 + ni * 16 + mrow) * 32 + quad * 8];
#pragma unroll
    for (int mi = 0; mi < 2; ++mi)
#pragma unroll
      for (int ni = 0; ni < 8; ++ni)
        acc[mi][ni] = __builtin_amdgcn_mfma_f32_16x16x32_f16(aF[mi], bF[ni], acc[mi][ni], 0, 0, 0);
  }

  // ---------- epilogue: +b1, LN2 stats (cross-wave via LDS atomics) ----------
  float b1v[8], g2v[8], bl2v[8];
#pragma unroll
  for (int ni = 0; ni < 8; ++ni) {
    int col = wave * 128 + ni * 16 + mrow;
    b1v[ni] = b1[col]; g2v[ni] = ln2g[col]; bl2v[ni] = ln2b[col];
  }
#pragma unroll
  for (int mi = 0; mi < 2; ++mi)
#pragma unroll
    for (int reg = 0; reg < 4; ++reg) {
      int r = mi * 16 + quad * 4 + reg;  // C/D layout: col=lane&15, row=quad*4+reg
      float s = 0.f, q = 0.f;
#pragma unroll
      for (int ni = 0; ni < 8; ++ni) {
        float v = acc[mi][ni][reg] + b1v[ni];
        acc[mi][ni][reg] = v;
        s += v; q += v * v;
      }
      s += __shfl_xor(s, 1); q += __shfl_xor(q, 1);
      s += __shfl_xor(s, 2); q += __shfl_xor(q, 2);
      s += __shfl_xor(s, 4); q += __shfl_xor(q, 4);
      s += __shfl_xor(s, 8); q += __shfl_xor(q, 8);
      if ((lane & 15) == 0) { atomicAdd(&sm.rsum[r], s); atomicAdd(&sm.rsq[r], q); }
    }
  __syncthreads();
  if (tid < MTILE) {
    float mean = sm.rsum[tid] * (1.f / 512.f);
    float var  = sm.rsq[tid] * (1.f / 512.f) - mean * mean;
    sm.mean2[tid] = mean;
    sm.rstd2[tid] = rsqrtf(var + 1e-5f);
  }
  __syncthreads();
#pragma unroll
  for (int mi = 0; mi < 2; ++mi)
#pragma unroll
    for (int ni = 0; ni < 8; ++ni)
#pragma unroll
      for (int reg = 0; reg < 4; ++reg) {
        int r = mi * 16 + quad * 4 + reg;
        int col = wave * 128 + ni * 16 + mrow;
        float v = (acc[mi][ni][reg] - sm.mean2[r]) * sm.rstd2[r] * g2v[ni] + bl2v[ni];
        X2[r * 520 + col] = f2h(selu_f(v));
      }
  __syncthreads();

  // ---------- GEMM2 (512->7) + tanh, W2 register-resident ----------
  float w2r[56];  // lane covers k = lane*8..+8, all 7 outputs
  {
    const float4* wp = (const float4*)W2 + lane * 14;
#pragma unroll
    for (int i = 0; i < 14; ++i) {
      float4 t = wp[i];
      w2r[i * 4 + 0] = t.x; w2r[i * 4 + 1] = t.y;
      w2r[i * 4 + 2] = t.z; w2r[i * 4 + 3] = t.w;
    }
  }
  float b2v = (lane < 7) ? b2[lane] : 0.f;
  for (int i = 0; i < 8; ++i) {
    int r = wave * 8 + i;
    f16x8 xv = *(const f16x8*)&X2[r * 520 + lane * 8];
    float o0 = 0, o1 = 0, o2 = 0, o3 = 0, o4 = 0, o5 = 0, o6 = 0;
#pragma unroll
    for (int e = 0; e < 8; ++e) {
      float xf = (float)xv[e];
      o0 += xf * w2r[e * 7 + 0]; o1 += xf * w2r[e * 7 + 1];
      o2 += xf * w2r[e * 7 + 2]; o3 += xf * w2r[e * 7 + 3];
      o4 += xf * w2r[e * 7 + 4]; o5 += xf * w2r[e * 7 + 5];
      o6 += xf * w2r[e * 7 + 6];
    }
#pragma unroll
    for (int d = 32; d > 0; d >>= 1) {
      o0 += __shfl_xor(o0, d); o1 += __shfl_xor(o1, d); o2 += __shfl_xor(o2, d);
      o3 += __shfl_xor(o3, d); o4 += __shfl_xor(o4, d); o5 += __shfl_xor(o5, d);
      o6 += __shfl_xor(o6, d);
    }
    if (lane < 7) {
      float ov = o0;
      if (lane == 1) ov = o1; else if (lane == 2) ov = o2;
      else if (lane == 3) ov = o3; else if (lane == 4) ov = o4;
      else if (lane == 5) ov = o5; else if (lane == 6) ov = o6;
      out[(size_t)(m0 + r) * 7 + lane] = tanhf(ov + b2v);
    }
  }
}

extern "C" void kernel_launch(void* const* d_in, const int* in_sizes, int n_in,
                              void* d_out, int out_size, void* d_ws, size_t ws_size,
                              hipStream_t stream) {
  const float* feat  = (const float*)d_in[0];
  const int*   crd   = (const int*)d_in[1];
  const float* jp    = (const float*)d_in[2];
  const float* jg    = (const float*)d_in[3];
  const float* ln1g  = (const float*)d_in[4];
  const float* ln1b  = (const float*)d_in[5];
  const float* W1    = (const float*)d_in[6];
  const float* b1    = (const float*)d_in[7];
  const float* ln2g  = (const float*)d_in[8];
  const float* ln2b  = (const float*)d_in[9];
  const float* W2    = (const float*)d_in[10];
  const float* b2    = (const float*)d_in[11];
  float* out = (float*)d_out;

  unsigned int*   mask = (unsigned int*)d_ws;
  unsigned short* W1t  = (unsigned short*)((char*)d_ws + W1T_OFF);

  hipMemsetAsync(mask, 0, (size_t)B_ROWS * 4, stream);
  scatter_mask<<<B_ROWS / 256, 256, 0, stream>>>(crd, mask);
  build_w1t<<<512, 544, 0, stream>>>(W1, W1t);
  actor_main<<<B_ROWS / MTILE, 256, 0, stream>>>(
      feat, mask, jp, jg, ln1g, ln1b, W1t, b1, ln2g, ln2b, W2, b2, out);
}